// Round 1
// baseline (2245.659 us; speedup 1.0000x reference)
//
#include <hip/hip_runtime.h>

#define B_ 4
#define H_ 16
#define S_ 2048
#define D_ 128
#define BH_ (B_*H_)
#define SCALE 0.08838834764831845f   // 1/sqrt(128)

#define MT 128          // q rows per workgroup
#define KT 64           // keys per chunk
#define KS_STRIDE 136   // 272B rows: 16B-aligned b128 frags, ~2-way banks
#define VS_STRIDE 140   // 280B rows: u16 gather ~2-way banks
#define PS_STRIDE 72    // 144B rows: 16B-aligned b128 frags

typedef __bf16 bf16x8 __attribute__((ext_vector_type(8)));
typedef __bf16 bf16x4 __attribute__((ext_vector_type(4)));
typedef float  f32x4  __attribute__((ext_vector_type(4)));

__device__ __forceinline__ bf16x4 cvt4(const float4 v) {
  bf16x4 w;
  w[0] = (__bf16)v.x; w[1] = (__bf16)v.y; w[2] = (__bf16)v.z; w[3] = (__bf16)v.w;
  return w;
}

__global__ __launch_bounds__(256, 2)
void attn_kernel(const float* __restrict__ Q, const float* __restrict__ K,
                 const float* __restrict__ V, const int* __restrict__ Mk,
                 float* __restrict__ outp, float* __restrict__ attnp)
{
  __shared__ __bf16 Ks[KT * KS_STRIDE];   // 17408 B
  __shared__ __bf16 Vs[KT * VS_STRIDE];   // 17920 B  (row-major [key][d])
  __shared__ __bf16 Ps[MT * PS_STRIDE];   // 18432 B  (P in [m][k] for A-frags)
  __shared__ float  rowsum_s[MT];         //   512 B

  const int tid  = threadIdx.x;
  const int lane = tid & 63;
  const int wave = tid >> 6;
  const int ln15 = lane & 15;
  const int q4   = lane >> 4;
  const int wm0  = wave * 32;             // wave's first q-row in tile

  const int bh = blockIdx.y;
  const int b  = bh >> 4;
  const int q0 = blockIdx.x * MT;

  const float* Qg = Q + (size_t)bh * S_ * D_;
  const float* Kg = K + (size_t)bh * S_ * D_;
  const float* Vg = V + (size_t)bh * S_ * D_;
  const int*   Mg = Mk + (size_t)b * S_ * S_;
  float* Og = outp  + (size_t)bh * S_ * D_;
  float* Ag = attnp + (size_t)bh * S_ * S_;

  // ---- preload Q fragments (A-layout: m=lane&15, k=(lane>>4)*8+j), scaled ----
  bf16x8 qf[2][4];
#pragma unroll
  for (int mt = 0; mt < 2; ++mt) {
    const float* qrow = Qg + (size_t)(q0 + wm0 + mt*16 + ln15) * D_ + q4*8;
#pragma unroll
    for (int kk = 0; kk < 4; ++kk) {
      const float4 a = *(const float4*)(qrow + kk*32);
      const float4 c = *(const float4*)(qrow + kk*32 + 4);
      bf16x8 f;
      f[0] = (__bf16)(a.x*SCALE); f[1] = (__bf16)(a.y*SCALE);
      f[2] = (__bf16)(a.z*SCALE); f[3] = (__bf16)(a.w*SCALE);
      f[4] = (__bf16)(c.x*SCALE); f[5] = (__bf16)(c.y*SCALE);
      f[6] = (__bf16)(c.z*SCALE); f[7] = (__bf16)(c.w*SCALE);
      qf[mt][kk] = f;
    }
  }

  // ================= PASS A: row sums of exp(masked scores) =================
  float rs[2][4] = {{0.f,0.f,0.f,0.f},{0.f,0.f,0.f,0.f}};
  for (int k0 = 0; k0 < S_; k0 += KT) {
    __syncthreads();
#pragma unroll
    for (int i = 0; i < 8; ++i) {               // stage K chunk (64x128 fp32 -> bf16)
      const int idx = i*256 + tid;
      const int r = idx >> 5, c4 = idx & 31;
      const float4 kv = *(const float4*)(Kg + (size_t)(k0 + r)*D_ + c4*4);
      *(bf16x4*)&Ks[r*KS_STRIDE + c4*4] = cvt4(kv);
    }
    __syncthreads();
#pragma unroll
    for (int nt = 0; nt < 4; ++nt) {
      bf16x8 kf[4];
#pragma unroll
      for (int kk = 0; kk < 4; ++kk)
        kf[kk] = *(const bf16x8*)&Ks[(nt*16 + ln15)*KS_STRIDE + kk*32 + q4*8];
      const int kcol = k0 + nt*16 + ln15;
#pragma unroll
      for (int mt = 0; mt < 2; ++mt) {
        f32x4 acc = {0.f,0.f,0.f,0.f};
#pragma unroll
        for (int kk = 0; kk < 4; ++kk)
          acc = __builtin_amdgcn_mfma_f32_16x16x32_bf16(qf[mt][kk], kf[kk], acc, 0,0,0);
        const int m0 = q0 + wm0 + mt*16 + q4*4;
#pragma unroll
        for (int r = 0; r < 4; ++r) {
          const int mv = Mg[(size_t)(m0 + r)*S_ + kcol];
          rs[mt][r] += mv ? __expf(acc[r]) : 0.f;
        }
      }
    }
  }
  // cross-lane reduce (cols live across the 16 lanes of each quad-group)
#pragma unroll
  for (int mt = 0; mt < 2; ++mt)
#pragma unroll
    for (int r = 0; r < 4; ++r) {
      float v = rs[mt][r];
      v += __shfl_xor(v, 1); v += __shfl_xor(v, 2);
      v += __shfl_xor(v, 4); v += __shfl_xor(v, 8);
      if (ln15 == 0) rowsum_s[wm0 + mt*16 + q4*4 + r] = v;
    }
  __syncthreads();
  float inv[2][4];
#pragma unroll
  for (int mt = 0; mt < 2; ++mt)
#pragma unroll
    for (int r = 0; r < 4; ++r)
      inv[mt][r] = 1.0f / fmaxf(rowsum_s[wm0 + mt*16 + q4*4 + r], 1e-30f);

  // ================= PASS B: write attn + accumulate PV =================
  f32x4 oacc[2][8];
#pragma unroll
  for (int mt = 0; mt < 2; ++mt)
#pragma unroll
    for (int dt = 0; dt < 8; ++dt)
      oacc[mt][dt] = (f32x4){0.f,0.f,0.f,0.f};

  for (int k0 = 0; k0 < S_; k0 += KT) {
    __syncthreads();
#pragma unroll
    for (int i = 0; i < 8; ++i) {               // stage K + V chunk
      const int idx = i*256 + tid;
      const int r = idx >> 5, c4 = idx & 31;
      const float4 kv = *(const float4*)(Kg + (size_t)(k0 + r)*D_ + c4*4);
      *(bf16x4*)&Ks[r*KS_STRIDE + c4*4] = cvt4(kv);
      const float4 vv = *(const float4*)(Vg + (size_t)(k0 + r)*D_ + c4*4);
      *(bf16x4*)&Vs[r*VS_STRIDE + c4*4] = cvt4(vv);
    }
    __syncthreads();

#pragma unroll
    for (int nt = 0; nt < 4; ++nt) {
      bf16x8 kf[4];
#pragma unroll
      for (int kk = 0; kk < 4; ++kk)
        kf[kk] = *(const bf16x8*)&Ks[(nt*16 + ln15)*KS_STRIDE + kk*32 + q4*8];
      const int kcol = k0 + nt*16 + ln15;
#pragma unroll
      for (int mt = 0; mt < 2; ++mt) {
        f32x4 acc = {0.f,0.f,0.f,0.f};
#pragma unroll
        for (int kk = 0; kk < 4; ++kk)
          acc = __builtin_amdgcn_mfma_f32_16x16x32_bf16(qf[mt][kk], kf[kk], acc, 0,0,0);
        const int m0 = q0 + wm0 + mt*16 + q4*4;
#pragma unroll
        for (int r = 0; r < 4; ++r) {
          const int mv = Mg[(size_t)(m0 + r)*S_ + kcol];
          const float p = mv ? __expf(acc[r]) : 0.f;
          const float a = p * inv[mt][r];
          __builtin_nontemporal_store(a, Ag + (size_t)(m0 + r)*S_ + kcol);
          Ps[(wm0 + mt*16 + q4*4 + r)*PS_STRIDE + nt*16 + ln15] = (__bf16)a;
        }
      }
    }

    // PV: out(32x128 per wave) += P(32x64) * V(64x128); P re-read in A-layout
#pragma unroll
    for (int kk2 = 0; kk2 < 2; ++kk2) {
      bf16x8 pf[2];
#pragma unroll
      for (int mt = 0; mt < 2; ++mt)
        pf[mt] = *(const bf16x8*)&Ps[(wm0 + mt*16 + ln15)*PS_STRIDE + kk2*32 + q4*8];
#pragma unroll
      for (int dt = 0; dt < 8; ++dt) {
        bf16x8 vf;                               // B-frag: n=lane&15, k=(lane>>4)*8+j
#pragma unroll
        for (int j = 0; j < 8; ++j)
          vf[j] = Vs[(kk2*32 + q4*8 + j)*VS_STRIDE + dt*16 + ln15];
#pragma unroll
        for (int mt = 0; mt < 2; ++mt)
          oacc[mt][dt] = __builtin_amdgcn_mfma_f32_16x16x32_bf16(pf[mt], vf, oacc[mt][dt], 0,0,0);
      }
    }
  }

  // ---- epilogue: out tile ----
#pragma unroll
  for (int mt = 0; mt < 2; ++mt) {
    const int m0 = q0 + wm0 + mt*16 + q4*4;
#pragma unroll
    for (int dt = 0; dt < 8; ++dt)
#pragma unroll
      for (int r = 0; r < 4; ++r)
        __builtin_nontemporal_store(oacc[mt][dt][r],
                                    Og + (size_t)(m0 + r)*D_ + dt*16 + ln15);
  }
}

extern "C" void kernel_launch(void* const* d_in, const int* in_sizes, int n_in,
                              void* d_out, int out_size, void* d_ws, size_t ws_size,
                              hipStream_t stream) {
  (void)in_sizes; (void)n_in; (void)d_ws; (void)ws_size; (void)out_size;
  const float* Q = (const float*)d_in[0];
  const float* K = (const float*)d_in[1];
  const float* V = (const float*)d_in[2];
  const int*   M = (const int*)d_in[3];
  float* outp  = (float*)d_out;
  float* attnp = outp + (size_t)B_ * H_ * S_ * D_;   // tuple order: (out, attn)
  dim3 grid(S_ / MT, BH_);
  attn_kernel<<<grid, 256, 0, stream>>>(Q, K, V, M, outp, attnp);
}